// Round 6
// baseline (305.874 us; speedup 1.0000x reference)
//
#include <hip/hip_runtime.h>
#include <stdint.h>

#define D_IN 128
#define D_OUT 128
#define NREL 8
#define NBASE 4

typedef __attribute__((ext_vector_type(8))) short short8;
typedef __attribute__((ext_vector_type(4))) float floatx4;

__device__ __forceinline__ unsigned short f2bf(float f) {
  unsigned int u = __float_as_uint(f);
  u += 0x7fffu + ((u >> 16) & 1u);
  return (unsigned short)(u >> 16);
}
__device__ __forceinline__ unsigned pack2bf(float lo, float hi) {
  return (unsigned)f2bf(lo) | ((unsigned)f2bf(hi) << 16);
}
__device__ __forceinline__ float bflo(unsigned int u) { return __uint_as_float(u << 16); }
__device__ __forceinline__ float bfhi(unsigned int u) { return __uint_as_float(u & 0xffff0000u); }

// ---------- 1) prep: zero counts + cast X fp32->bf16 + build W2T ----------
// W2T[o][c] = w_bases[b][k][o], c = k*4+b  (bf16, [128][512])
__global__ void k_prep(const float4* __restrict__ X, ushort4* __restrict__ Xb, int n4,
                       const float* __restrict__ w_bases, unsigned short* __restrict__ W2T,
                       uint4* __restrict__ counts4, int nc4) {
  int i = blockIdx.x * blockDim.x + threadIdx.x;
  if (i < n4) {
    float4 v = X[i];
    ushort4 o;
    o.x = f2bf(v.x); o.y = f2bf(v.y); o.z = f2bf(v.z); o.w = f2bf(v.w);
    Xb[i] = o;
  }
  if (i < 128 * 512) {
    int o = i >> 9, c = i & 511;
    int k = c >> 2, b = c & 3;
    W2T[i] = f2bf(w_bases[(b * D_IN + k) * D_OUT + o]);
  }
  if (i < nc4) counts4[i] = make_uint4(0u, 0u, 0u, 0u);
}

// ---------- 2) CSR build ----------
__global__ void k_count(const int* __restrict__ dst, int* __restrict__ counts, int E) {
  int i = blockIdx.x * blockDim.x + threadIdx.x;
  if (i < E) atomicAdd(&counts[dst[i]], 1);
}

__global__ void k_scan1(const int* __restrict__ counts, int* __restrict__ localsc,
                        int* __restrict__ bsum, int Nn) {
  __shared__ int s[256];
  int i = blockIdx.x * 256 + threadIdx.x;
  int v = (i < Nn) ? counts[i] : 0;
  s[threadIdx.x] = v;
  __syncthreads();
  for (int off = 1; off < 256; off <<= 1) {
    int t = 0;
    if (threadIdx.x >= off) t = s[threadIdx.x - off];
    __syncthreads();
    s[threadIdx.x] += t;
    __syncthreads();
  }
  if (i < Nn) localsc[i] = s[threadIdx.x] - v;
  if (threadIdx.x == 255) bsum[blockIdx.x] = s[255];
}

// fused scan2+scan3: each block redundantly reduces bsum[0..blockIdx.x) (tiny)
__global__ void k_scan23(const int* __restrict__ localsc, const int* __restrict__ bsum,
                         int* __restrict__ offsets, int* __restrict__ cursor, int Nn, int E) {
  __shared__ int red[256];
  int acc = 0;
  for (int j = threadIdx.x; j < blockIdx.x; j += 256) acc += bsum[j];
  red[threadIdx.x] = acc;
  __syncthreads();
  for (int off = 128; off > 0; off >>= 1) {
    if (threadIdx.x < off) red[threadIdx.x] += red[threadIdx.x + off];
    __syncthreads();
  }
  int pref = red[0];
  int i = blockIdx.x * 256 + threadIdx.x;
  if (i < Nn) {
    int v = localsc[i] + pref;
    offsets[i] = v;
    cursor[i] = v;
  }
  if (i == 0) offsets[Nn] = E;
}

__global__ void k_bucket(const int* __restrict__ src, const int* __restrict__ dst,
                         const int* __restrict__ rel, const float* __restrict__ val,
                         int* __restrict__ cursor, uint2* __restrict__ bucket, int E) {
  int i = blockIdx.x * blockDim.x + threadIdx.x;
  if (i >= E) return;
  int d = dst[i];
  int pos = atomicAdd(&cursor[d], 1);
  bucket[pos] = make_uint2((unsigned)src[i] | ((unsigned)rel[i] << 21), __float_as_uint(val[i]));
}

// ---------- 3) fused: per-dst basis aggregation (LDS) + MFMA transform ----------
struct Acc8 {
  float a00, a10, a20, a30, a01, a11, a21, a31;
  __device__ __forceinline__ void init() {
    a00 = a10 = a20 = a30 = a01 = a11 = a21 = a31 = 0.f;
  }
  __device__ __forceinline__ void add(uint2 m, unsigned xw, const float* wr) {
    float val = __uint_as_float(m.y);
    const float* w = &wr[(m.x >> 21) * 4];
    float c0 = val * w[0], c1 = val * w[1], c2 = val * w[2], c3 = val * w[3];
    float xl = bflo(xw), xh = bfhi(xw);
    a00 += c0 * xl; a10 += c1 * xl; a20 += c2 * xl; a30 += c3 * xl;
    a01 += c0 * xh; a11 += c1 * xh; a21 += c2 * xh; a31 += c3 * xh;
  }
};

// Block = 8 waves (512 thr), 32 dst rows. Phase 1: STATIC interleaved rows —
// wave w handles rows {w, w+8, w+16, w+24} (no cross-wave comms; R5's dynamic
// LDS-atomic grab raced intermittently under graph replay). Phase 2:
// 32x512 @ 512x128 bf16 MFMA; wave w: row-half w>>2, col base (w&3)*32.
// launch_bounds(512,8): 4 blocks/CU = 32 waves/CU.
__global__ __launch_bounds__(512, 8)
void k_agg_gemm(const uint2* __restrict__ bucket, const int* __restrict__ offsets,
                const float* __restrict__ w_rel_g, const unsigned* __restrict__ Xb2,
                const unsigned short* __restrict__ W2T, float* __restrict__ out, int Nn) {
  __shared__ unsigned short aggS[32][520];
  __shared__ float wr[NREL * NBASE];
  if (threadIdx.x < NREL * NBASE) wr[threadIdx.x] = w_rel_g[threadIdx.x];
  __syncthreads();

  const int wave = threadIdx.x >> 6, lane = threadIdx.x & 63;

  // ---- phase 1: 4 interleaved rows per wave ----
#pragma unroll
  for (int j = 0; j < 4; ++j) {
    const int lrow = wave + j * 8;
    const int dst = blockIdx.x * 32 + lrow;
    Acc8 A;
    A.init();
    if (dst < Nn) {
      const int s = offsets[dst], e = offsets[dst + 1];
      int i = s;
      for (; i + 4 <= e; i += 4) {
        uint2 m0 = bucket[i], m1 = bucket[i + 1], m2 = bucket[i + 2], m3 = bucket[i + 3];
        unsigned y0 = Xb2[((size_t)(m0.x & 0x1FFFFFu) << 6) + lane];
        unsigned y1 = Xb2[((size_t)(m1.x & 0x1FFFFFu) << 6) + lane];
        unsigned y2 = Xb2[((size_t)(m2.x & 0x1FFFFFu) << 6) + lane];
        unsigned y3 = Xb2[((size_t)(m3.x & 0x1FFFFFu) << 6) + lane];
        A.add(m0, y0, wr); A.add(m1, y1, wr); A.add(m2, y2, wr); A.add(m3, y3, wr);
      }
      for (; i < e; ++i) {
        uint2 m = bucket[i];
        unsigned y = Xb2[((size_t)(m.x & 0x1FFFFFu) << 6) + lane];
        A.add(m, y, wr);
      }
    }
    uint4 o;
    o.x = pack2bf(A.a00, A.a10);
    o.y = pack2bf(A.a20, A.a30);
    o.z = pack2bf(A.a01, A.a11);
    o.w = pack2bf(A.a21, A.a31);
    *(uint4*)&aggS[lrow][lane * 8] = o;  // contiguous 1 KB wave write
  }
  __syncthreads();

  // ---- phase 2: 32x128 output tile via 16x16x32 MFMA, K=512 ----
  const int q = lane >> 4, r16 = lane & 15;
  const int ihalf = wave >> 2;           // row-half: rows ihalf*16..+15
  const int jb = (wave & 3) * 32;        // col-pair base
  const floatx4 zero = {0.f, 0.f, 0.f, 0.f};
  floatx4 acc0 = zero, acc1 = zero;

#pragma unroll 4
  for (int k0 = 0; k0 < 512; k0 += 32) {
    int ka = k0 + q * 8;
    short8 af = *(const short8*)&aggS[ihalf * 16 + r16][ka];
    short8 bf0 = *(const short8*)(W2T + (size_t)(jb + r16) * 512 + ka);
    short8 bf1 = *(const short8*)(W2T + (size_t)(jb + 16 + r16) * 512 + ka);
    acc0 = __builtin_amdgcn_mfma_f32_16x16x32_bf16(af, bf0, acc0, 0, 0, 0);
    acc1 = __builtin_amdgcn_mfma_f32_16x16x32_bf16(af, bf1, acc1, 0, 0, 0);
  }

  // epilogue: C/D layout col=lane&15, row=(lane>>4)*4+p  [m89/m91-verified]
#pragma unroll
  for (int p = 0; p < 4; ++p) {
    int grow = blockIdx.x * 32 + ihalf * 16 + q * 4 + p;
    if (grow < Nn) {
      out[(size_t)grow * 128 + jb + r16] = acc0[p];
      out[(size_t)grow * 128 + jb + 16 + r16] = acc1[p];
    }
  }
}

extern "C" void kernel_launch(void* const* d_in, const int* in_sizes, int n_in,
                              void* d_out, int out_size, void* d_ws, size_t ws_size,
                              hipStream_t stream) {
  const float* X = (const float*)d_in[0];
  const int* esrc = (const int*)d_in[1];
  const int* edst = (const int*)d_in[2];
  const int* erel = (const int*)d_in[3];
  const float* eval_ = (const float*)d_in[4];
  const float* w_bases = (const float*)d_in[5];
  const float* w_rel = (const float*)d_in[6];
  const int Nn = in_sizes[0] / D_IN;  // 100000
  const int E = in_sizes[1];          // 640000

  char* ws = (char*)d_ws;
  size_t off = 0;
  auto alloc = [&](size_t bytes) -> char* {
    char* p = ws + off;
    off += (bytes + 255) & ~(size_t)255;
    return p;
  };
  unsigned short* Xb = (unsigned short*)alloc((size_t)Nn * D_IN * 2);     // 25.6 MB
  unsigned short* W2T = (unsigned short*)alloc((size_t)128 * 512 * 2);    // 128 KB
  int* counts = (int*)alloc((size_t)Nn * 4);
  int* cursor = (int*)alloc((size_t)Nn * 4);
  int* offsets = (int*)alloc((size_t)(Nn + 1) * 4);
  int* localsc = (int*)alloc((size_t)Nn * 4);
  int* bsum = (int*)alloc(4096);
  uint2* bucket = (uint2*)alloc((size_t)E * 8);                           // 5.1 MB
  (void)ws_size;

  int n4 = Nn * D_IN / 4;  // 3.2M
  int nc4 = Nn / 4;        // counts as uint4
  k_prep<<<(n4 + 255) / 256, 256, 0, stream>>>((const float4*)X, (ushort4*)Xb, n4,
                                               w_bases, W2T, (uint4*)counts, nc4);

  k_count<<<(E + 255) / 256, 256, 0, stream>>>(edst, counts, E);
  int nb = (Nn + 255) / 256;
  k_scan1<<<nb, 256, 0, stream>>>(counts, localsc, bsum, Nn);
  k_scan23<<<nb, 256, 0, stream>>>(localsc, bsum, offsets, cursor, Nn, E);
  k_bucket<<<(E + 255) / 256, 256, 0, stream>>>(esrc, edst, erel, eval_, cursor, bucket, E);

  // fused aggregation + transform (512 thr, 32 dsts/block, static interleave)
  k_agg_gemm<<<(Nn + 31) / 32, 512, 0, stream>>>(bucket, offsets, w_rel,
                                                 (const unsigned*)Xb, W2T,
                                                 (float*)d_out, Nn);
}